// Round 7
// baseline (311.537 us; speedup 1.0000x reference)
//
#include <hip/hip_runtime.h>
#include <hip/hip_bf16.h>
#include <math.h>

typedef unsigned int u32;

#define LRELU(a) ((a) > 0.f ? (a) : 0.2f * (a))

#define FIX_SCALE 67108864.0f          // 2^26 fixed-point for attr sums
#define FIX_INV   (1.0f / 67108864.0f)
#define CNT_SHIFT 40
#define SUM_MASK  0xFFFFFFFFFFULL

// round-to-nearest-even f32 -> bf16 bits
__device__ __forceinline__ u32 f2bf(float f) {
    u32 u = __float_as_uint(f);
    return (u + 0x7fffu + ((u >> 16) & 1u)) >> 16;
}

__device__ __forceinline__ float readlane_f(float v, int j) {
    return __int_as_float(__builtin_amdgcn_readlane(__float_as_int(v), j));
}

// ---------------- CSR build ----------------
// hist[d] packs {count << 40 | sum(attr * 2^26)} in one u64 atomic per edge.

__global__ void hist_kernel(const int* __restrict__ dst, const float* __restrict__ eattr,
                            unsigned long long* __restrict__ hist, int E) {
    int e = blockIdx.x * blockDim.x + threadIdx.x;
    if (e < E) {
        int d = dst[e];
        unsigned long long v = (1ULL << CNT_SHIFT) |
                               (unsigned long long)(eattr[e] * FIX_SCALE + 0.5f);
        atomicAdd(&hist[d], v);
    }
}

// 3-phase parallel exclusive scan over (cnt[n]+1).

__global__ __launch_bounds__(256) void scan_phase1(const unsigned long long* __restrict__ hist,
                                                   int* __restrict__ block_sum, int N) {
    int t = threadIdx.x;
    int n = blockIdx.x * 256 + t;
    int v = (n < N) ? (int)(hist[n] >> CNT_SHIFT) + 1 : 0;  // +1 self loop
#pragma unroll
    for (int m = 32; m >= 1; m >>= 1) v += __shfl_xor(v, m);
    __shared__ int ws[4];
    if ((t & 63) == 0) ws[t >> 6] = v;
    __syncthreads();
    if (t == 0) block_sum[blockIdx.x] = ws[0] + ws[1] + ws[2] + ws[3];
}

__global__ __launch_bounds__(1024) void scan_phase2(const int* __restrict__ block_sum,
                                                    int* __restrict__ block_off,
                                                    int* __restrict__ row_ptr, int B, int N) {
    __shared__ int s[1024];
    int t = threadIdx.x;
    int v = (t < B) ? block_sum[t] : 0;
    s[t] = v;
    __syncthreads();
    for (int off = 1; off < 1024; off <<= 1) {
        int u = (t >= off) ? s[t - off] : 0;
        __syncthreads();
        s[t] += u;
        __syncthreads();
    }
    if (t < B) block_off[t] = s[t] - v;       // exclusive offset for block t
    if (t == 1023) row_ptr[N] = s[1023];      // total = E + N
}

__global__ __launch_bounds__(256) void scan_phase3(const unsigned long long* __restrict__ hist,
                                                   const int* __restrict__ block_off,
                                                   int* __restrict__ row_ptr, int* __restrict__ cursor,
                                                   int2* __restrict__ col, int N) {
    int t = threadIdx.x;
    int lane = t & 63;
    int n = blockIdx.x * 256 + t;
    unsigned long long hv = (n < N) ? hist[n] : 0ULL;
    int c = (n < N) ? (int)(hv >> CNT_SHIFT) + 1 : 0;
    // inclusive scan within wave
    int v = c;
#pragma unroll
    for (int m = 1; m < 64; m <<= 1) {
        int u = __shfl_up(v, m);
        if (lane >= m) v += u;
    }
    __shared__ int wsum[4];
    if (lane == 63) wsum[t >> 6] = v;
    __syncthreads();
    int w = t >> 6;
    int wadd = 0;
#pragma unroll
    for (int i = 0; i < 3; i++) wadd += (i < w) ? wsum[i] : 0;
    int base = block_off[blockIdx.x] + wadd + v - c;  // exclusive position
    if (n < N) {
        row_ptr[n] = base;
        float asum = (float)(hv & SUM_MASK) * FIX_INV;
        float la = asum / fmaxf((float)(c - 1), 1.f);  // fill_value='mean' self-loop attr
        col[base] = make_int2(n, __float_as_int(la));   // self loop first in row
        cursor[n] = base + 1;
    }
}

__global__ void scatter_kernel(const int* __restrict__ src, const int* __restrict__ dst,
                               const float* __restrict__ eattr, int* __restrict__ cursor,
                               int2* __restrict__ col, int E) {
    int e = blockIdx.x * blockDim.x + threadIdx.x;
    if (e < E) {
        int d = dst[e];
        int pos = atomicAdd(&cursor[d], 1);
        col[pos] = make_int2(src[e], __float_as_int(eattr[e]));
    }
}

// ---------------- prep: transpose W's (for scalar streaming) + we_dot scalars ----------------

__global__ __launch_bounds__(256) void prep_kernel(
        const float* __restrict__ W1, const float* __restrict__ W2,
        const float* __restrict__ We1, const float* __restrict__ ae1,
        const float* __restrict__ We2, const float* __restrict__ ae2,
        float* __restrict__ Wt1, float* __restrict__ Wt2, float* __restrict__ we_dot) {
    int t = threadIdx.x;
    if (t < 128) {
#pragma unroll
        for (int k = 0; k < 5; k++)  Wt1[t * 5 + k]  = W1[k * 128 + t];
#pragma unroll
        for (int k = 0; k < 64; k++) Wt2[t * 64 + k] = W2[k * 128 + t];
    }
    int g = t >> 6, lane = t & 63;          // g = layer*2 + h
    const float* We = (g & 2) ? We2 : We1;
    const float* ae = (g & 2) ? ae2 : ae1;
    int h = g & 1;
    float v = We[h * 64 + lane] * ae[h * 64 + lane];
#pragma unroll
    for (int m = 32; m >= 1; m >>= 1) v += __shfl_xor(v, m);
    if (lane == 0) we_dot[g] = v;
}

// ---------------- node projection: lane = node, wave = head; W streamed via scalar loads ----
// xhb[n][w] (w=0..63) packs channels {2w,2w+1} as bf16x2; ch 0-63 = head0, 64-127 = head1.

template<int FIN>
__global__ __launch_bounds__(256) void node_proj2(
        const float* __restrict__ feat, const float* __restrict__ Wt,
        const float* __restrict__ as_, const float* __restrict__ ad_,
        u32* __restrict__ xhb, float* __restrict__ al_s, float* __restrict__ al_d, int N) {
    int lane = threadIdx.x & 63;
    int gw = __builtin_amdgcn_readfirstlane(blockIdx.x * 4 + (threadIdx.x >> 6));
    int h  = gw & 1;            // uniform (SGPR) -> Wt/as/ad reads scalarize
    int nb = gw >> 1;
    int n = nb * 64 + lane;
    if (n >= N) return;

    float f[FIN];
    const float* fr = feat + (size_t)n * FIN;
    if constexpr (FIN == 64) {
        const float4* f4 = (const float4*)fr;
#pragma unroll
        for (int q = 0; q < 16; q++) {
            float4 v = f4[q];
            f[4*q] = v.x; f[4*q+1] = v.y; f[4*q+2] = v.z; f[4*q+3] = v.w;
        }
    } else {
#pragma unroll
        for (int k = 0; k < FIN; k++) f[k] = fr[k];
    }

    const float* wbase = Wt + (size_t)(h * 64) * FIN;   // this head's 64 output rows
    const float* asl = as_ + h * 64;
    const float* adl = ad_ + h * 64;
    float vs = 0.f, vd = 0.f;
    u32* dst = xhb + (size_t)n * 64 + h * 32;

    for (int j4 = 0; j4 < 64; j4 += 4) {
        const float* w0 = wbase + (size_t)j4 * FIN;
        float o0 = 0.f, o1 = 0.f, o2 = 0.f, o3 = 0.f;
#pragma unroll
        for (int k = 0; k < FIN; k++) {
            float fk = f[k];
            o0 += fk * w0[k];
            o1 += fk * w0[FIN + k];
            o2 += fk * w0[2 * FIN + k];
            o3 += fk * w0[3 * FIN + k];
        }
        vs += o0 * asl[j4] + o1 * asl[j4+1] + o2 * asl[j4+2] + o3 * asl[j4+3];
        vd += o0 * adl[j4] + o1 * adl[j4+1] + o2 * adl[j4+2] + o3 * adl[j4+3];
        uint2 pw = make_uint2((f2bf(o1) << 16) | f2bf(o0), (f2bf(o3) << 16) | f2bf(o2));
        *((uint2*)(dst + (j4 >> 1))) = pw;
    }
    al_s[n * 2 + h] = vs;
    al_d[n * 2 + h] = vd;
}

// ---------------- edge aggregation: wave per dst node, 4 waves/block, no LDS ----------------
// lane owns packed word `lane` = channels {2*lane,2*lane+1}; lanes<32 head0, lanes>=32 head1.

__global__ __launch_bounds__(256) void edge_aggr2(
        const int* __restrict__ row_ptr, const int2* __restrict__ col,
        const float2* __restrict__ al_s, const float2* __restrict__ al_d,
        const u32* __restrict__ xhb,
        const float* __restrict__ bias, const float* __restrict__ we_dot, int layer,
        float* __restrict__ out, int N) {
    int lane = threadIdx.x & 63;
    int n = blockIdx.x * 4 + (threadIdx.x >> 6);
    if (n >= N) return;
    int start = row_ptr[n], end = row_ptr[n + 1];
    int cnt = end - start;
    float we0 = we_dot[layer * 2], we1 = we_dot[layer * 2 + 1];
    float2 ald = al_d[n];
    bool lo = lane < 32;

    float accx = 0.f, accy = 0.f, den0 = 0.f, den1 = 0.f;

    if (cnt <= 64) {
        // ---- fast path: single chunk, alpha once, weights broadcast via readlane ----
        float a0 = -INFINITY, a1 = -INFINITY;
        int sc = 0;
        if (lane < cnt) {
            int2 ce = col[start + lane];
            sc = ce.x;
            float at = __int_as_float(ce.y);
            float2 als = al_s[sc];
            a0 = LRELU(als.x + ald.x + we0 * at);
            a1 = LRELU(als.y + ald.y + we1 * at);
        }
        float m0 = a0, m1 = a1;
#pragma unroll
        for (int m = 32; m >= 1; m >>= 1) {
            m0 = fmaxf(m0, __shfl_xor(m0, m));
            m1 = fmaxf(m1, __shfl_xor(m1, m));
        }
        float e0 = 0.f, e1 = 0.f;
        if (lane < cnt) {
            e0 = __expf(a0 - m0);
            e1 = __expf(a1 - m1);
        }
        den0 = e0; den1 = e1;
#pragma unroll 4
        for (int j = 0; j < cnt; j++) {
            int sj  = __builtin_amdgcn_readlane(sc, j);   // uniform -> SGPR base
            float w0 = readlane_f(e0, j);
            float w1 = readlane_f(e1, j);
            float w = lo ? w0 : w1;
            u32 v = xhb[(size_t)sj * 64 + lane];
            accx += w * __uint_as_float(v << 16);
            accy += w * __uint_as_float(v & 0xffff0000u);
        }
    } else {
        // ---- general path (cnt > 64): chunked, same broadcast scheme ----
        float m0 = -INFINITY, m1 = -INFINITY;
        for (int i = start + lane; i < end; i += 64) {
            int2 ce = col[i];
            float at = __int_as_float(ce.y);
            float2 als = al_s[ce.x];
            m0 = fmaxf(m0, LRELU(als.x + ald.x + we0 * at));
            m1 = fmaxf(m1, LRELU(als.y + ald.y + we1 * at));
        }
#pragma unroll
        for (int m = 32; m >= 1; m >>= 1) {
            m0 = fmaxf(m0, __shfl_xor(m0, m));
            m1 = fmaxf(m1, __shfl_xor(m1, m));
        }
        for (int cs = start; cs < end; cs += 64) {
            int i = cs + lane;
            float e0 = 0.f, e1 = 0.f;
            int sc = 0;
            if (i < end) {
                int2 ce = col[i];
                sc = ce.x;
                float at = __int_as_float(ce.y);
                float2 als = al_s[sc];
                e0 = __expf(LRELU(als.x + ald.x + we0 * at) - m0);
                e1 = __expf(LRELU(als.y + ald.y + we1 * at) - m1);
            }
            den0 += e0; den1 += e1;
            int c2 = min(64, end - cs);
#pragma unroll 4
            for (int j = 0; j < c2; j++) {
                int sj  = __builtin_amdgcn_readlane(sc, j);
                float w0 = readlane_f(e0, j);
                float w1 = readlane_f(e1, j);
                float w = lo ? w0 : w1;
                u32 v = xhb[(size_t)sj * 64 + lane];
                accx += w * __uint_as_float(v << 16);
                accy += w * __uint_as_float(v & 0xffff0000u);
            }
        }
    }

#pragma unroll
    for (int m = 32; m >= 1; m >>= 1) {
        den0 += __shfl_xor(den0, m);
        den1 += __shfl_xor(den1, m);
    }
    float inv0 = 1.f / (den0 + 1e-16f), inv1 = 1.f / (den1 + 1e-16f);
    float px = __shfl_xor(accx, 32);   // partner head's partials, same channels
    float py = __shfl_xor(accy, 32);
    if (lo) {
        float2 bv = ((const float2*)bias)[lane];
        float ox = 0.5f * (accx * inv0 + px * inv1) + bv.x;
        float oy = 0.5f * (accy * inv0 + py * inv1) + bv.y;
        ((float2*)out)[(size_t)n * 32 + lane] = make_float2(fmaxf(ox, 0.f), fmaxf(oy, 0.f));
    }
}

// ---------------- pooling: hierarchical (LDS bins -> few global atomics) ----------------

__global__ __launch_bounds__(256) void pool_kernel(const float* __restrict__ feat,
                                                   const float* __restrict__ Wlin, const int* __restrict__ batch,
                                                   float* __restrict__ pool_sum, int* __restrict__ pool_cnt, int N) {
    __shared__ float s_sum[64];
    __shared__ int s_cnt[64];
    int t = threadIdx.x;
    if (t < 64) { s_sum[t] = 0.f; s_cnt[t] = 0; }
    __syncthreads();

    int nblk = gridDim.x;
    int chunk = (N + nblk - 1) / nblk;
    int lo = blockIdx.x * chunk;
    int hi = min(lo + chunk, N);
    int lane = t & 63;
    float wl = Wlin[lane];

    for (int node = lo + (t >> 6); node < hi; node += 4) {
        float v = feat[(size_t)node * 64 + lane] * wl;
#pragma unroll
        for (int m = 32; m >= 1; m >>= 1) v += __shfl_xor(v, m);
        if (lane == 0) {
            int g = batch[node];
            atomicAdd(&s_sum[g], v);
            atomicAdd(&s_cnt[g], 1);
        }
    }
    __syncthreads();
    if (t < 64 && s_cnt[t] > 0) {
        atomicAdd(&pool_sum[t], s_sum[t]);
        atomicAdd(&pool_cnt[t], s_cnt[t]);
    }
}

__global__ void final_kernel(const float* __restrict__ pool_sum, const int* __restrict__ pool_cnt,
                             const float* __restrict__ blin, float* __restrict__ out) {
    int g = threadIdx.x;
    if (g < 64) out[g] = pool_sum[g] / fmaxf((float)pool_cnt[g], 1.f) + blin[0];
}

// ---------------- launch ----------------

extern "C" void kernel_launch(void* const* d_in, const int* in_sizes, int n_in,
                              void* d_out, int out_size, void* d_ws, size_t ws_size,
                              hipStream_t stream) {
    const float* x     = (const float*)d_in[0];
    const int*   ei    = (const int*)d_in[1];
    const float* eattr = (const float*)d_in[2];
    const int*   batch = (const int*)d_in[3];
    const float* W1  = (const float*)d_in[4];
    const float* as1 = (const float*)d_in[5];
    const float* ad1 = (const float*)d_in[6];
    const float* We1 = (const float*)d_in[7];
    const float* ae1 = (const float*)d_in[8];
    const float* b1  = (const float*)d_in[9];
    const float* W2  = (const float*)d_in[10];
    const float* as2 = (const float*)d_in[11];
    const float* ad2 = (const float*)d_in[12];
    const float* We2 = (const float*)d_in[13];
    const float* ae2 = (const float*)d_in[14];
    const float* b2  = (const float*)d_in[15];
    const float* Wlin = (const float*)d_in[16];
    const float* blin = (const float*)d_in[17];
    float* out = (float*)d_out;

    int N = in_sizes[0] / 5;
    int E = in_sizes[1] / 2;
    size_t EP = (size_t)E + N;
    const int* src0 = ei;
    const int* dst0 = ei + E;
    int B = (N + 255) / 256;   // blocks for node-chunked scan (must be <= 1024)

    char* ws = (char*)d_ws;
    size_t off = 0;
    auto alloc = [&](size_t bytes) {
        void* p = ws + off;
        off = (off + bytes + 255) & ~(size_t)255;
        return p;
    };
    unsigned long long* hist = (unsigned long long*)alloc((size_t)N * 8);
    int*   row_ptr  = (int*)  alloc((size_t)(N + 1) * 4);
    int*   cursor   = (int*)  alloc((size_t)N * 4);
    int2*  col      = (int2*) alloc(EP * 8);
    int*   block_sum= (int*)  alloc((size_t)1024 * 4);
    int*   block_off= (int*)  alloc((size_t)1024 * 4);
    float* al_s     = (float*)alloc((size_t)N * 2 * 4);
    float* al_d     = (float*)alloc((size_t)N * 2 * 4);
    u32*   xhb      = (u32*)  alloc((size_t)N * 64 * 4);   // packed bf16x2
    float* feat1    = (float*)alloc((size_t)N * 64 * 4);
    float* feat2    = (float*)alloc((size_t)N * 64 * 4);
    float* Wt1      = (float*)alloc((size_t)128 * 5 * 4);
    float* Wt2      = (float*)alloc((size_t)128 * 64 * 4);
    float* we_dot   = (float*)alloc(4 * 4);
    float* pool_sum = (float*)alloc(64 * 4);
    int*   pool_cnt = (int*)  alloc(64 * 4);

    hipMemsetAsync(hist, 0, (size_t)N * 8, stream);
    hipMemsetAsync(block_sum, 0, (size_t)1024 * 4, stream);
    hipMemsetAsync(pool_sum, 0, 64 * 4, stream);
    hipMemsetAsync(pool_cnt, 0, 64 * 4, stream);

    hist_kernel<<<(E + 255) / 256, 256, 0, stream>>>(dst0, eattr, hist, E);
    scan_phase1<<<B, 256, 0, stream>>>(hist, block_sum, N);
    scan_phase2<<<1, 1024, 0, stream>>>(block_sum, block_off, row_ptr, B, N);
    scan_phase3<<<B, 256, 0, stream>>>(hist, block_off, row_ptr, cursor, col, N);
    scatter_kernel<<<(E + 255) / 256, 256, 0, stream>>>(src0, dst0, eattr, cursor, col, E);
    prep_kernel<<<1, 256, 0, stream>>>(W1, W2, We1, ae1, We2, ae2, Wt1, Wt2, we_dot);

    int nw = (N + 63) / 64;                 // node-waves per head
    int npb = (2 * nw + 3) / 4;             // blocks for node_proj2 (4 waves each)
    int eab = (N + 3) / 4;                  // blocks for edge_aggr2 (4 waves each)

    // layer 1
    node_proj2<5><<<npb, 256, 0, stream>>>(x, Wt1, as1, ad1, xhb, al_s, al_d, N);
    edge_aggr2<<<eab, 256, 0, stream>>>(row_ptr, col, (const float2*)al_s, (const float2*)al_d,
                                        xhb, b1, we_dot, 0, feat1, N);
    // layer 2
    node_proj2<64><<<npb, 256, 0, stream>>>(feat1, Wt2, as2, ad2, xhb, al_s, al_d, N);
    edge_aggr2<<<eab, 256, 0, stream>>>(row_ptr, col, (const float2*)al_s, (const float2*)al_d,
                                        xhb, b2, we_dot, 1, feat2, N);
    // pool + linear (hierarchical: LDS bins then ~2 global atomics per block)
    pool_kernel<<<512, 256, 0, stream>>>(feat2, Wlin, batch, pool_sum, pool_cnt, N);
    final_kernel<<<1, 64, 0, stream>>>(pool_sum, pool_cnt, blin, out);
}

// Round 8
// 228.381 us; speedup vs baseline: 1.3641x; 1.3641x over previous
//
#include <hip/hip_runtime.h>
#include <hip/hip_bf16.h>
#include <math.h>

typedef unsigned int u32;

#define LRELU(a) ((a) > 0.f ? (a) : 0.2f * (a))

#define FIX_SCALE 67108864.0f          // 2^26 fixed-point for attr sums
#define FIX_INV   (1.0f / 67108864.0f)
#define CNT_SHIFT 40
#define SUM_MASK  0xFFFFFFFFFFULL

// round-to-nearest-even f32 -> bf16 bits
__device__ __forceinline__ u32 f2bf(float f) {
    u32 u = __float_as_uint(f);
    return (u + 0x7fffu + ((u >> 16) & 1u)) >> 16;
}

// ---------------- CSR build ----------------
// Pass 1: one u64 atomic per edge; returned old value's count field = slot index.
// hist[d] packs {count << 40 | sum(attr * 2^26)}.

__global__ void hist_pos_kernel(const int* __restrict__ dst, const float* __restrict__ eattr,
                                unsigned long long* __restrict__ hist, int* __restrict__ pos, int E) {
    int e = blockIdx.x * blockDim.x + threadIdx.x;
    if (e < E) {
        int d = dst[e];
        unsigned long long v = (1ULL << CNT_SHIFT) |
                               (unsigned long long)(eattr[e] * FIX_SCALE + 0.5f);
        unsigned long long old = atomicAdd(&hist[d], v);
        pos[e] = (int)(old >> CNT_SHIFT);
    }
}

// 3-phase parallel exclusive scan over (cnt[n]+1).

__global__ __launch_bounds__(256) void scan_phase1(const unsigned long long* __restrict__ hist,
                                                   int* __restrict__ block_sum, int N) {
    int t = threadIdx.x;
    int n = blockIdx.x * 256 + t;
    int v = (n < N) ? (int)(hist[n] >> CNT_SHIFT) + 1 : 0;  // +1 self loop
#pragma unroll
    for (int m = 32; m >= 1; m >>= 1) v += __shfl_xor(v, m);
    __shared__ int ws[4];
    if ((t & 63) == 0) ws[t >> 6] = v;
    __syncthreads();
    if (t == 0) block_sum[blockIdx.x] = ws[0] + ws[1] + ws[2] + ws[3];
}

__global__ __launch_bounds__(1024) void scan_phase2(const int* __restrict__ block_sum,
                                                    int* __restrict__ block_off,
                                                    int* __restrict__ row_ptr, int B, int N) {
    __shared__ int s[1024];
    int t = threadIdx.x;
    int v = (t < B) ? block_sum[t] : 0;
    s[t] = v;
    __syncthreads();
    for (int off = 1; off < 1024; off <<= 1) {
        int u = (t >= off) ? s[t - off] : 0;
        __syncthreads();
        s[t] += u;
        __syncthreads();
    }
    if (t < B) block_off[t] = s[t] - v;       // exclusive offset for block t
    if (t == 1023) row_ptr[N] = s[1023];      // total = E + N
}

__global__ __launch_bounds__(256) void scan_phase3(const unsigned long long* __restrict__ hist,
                                                   const int* __restrict__ block_off,
                                                   int* __restrict__ row_ptr,
                                                   int2* __restrict__ col, int N) {
    int t = threadIdx.x;
    int lane = t & 63;
    int n = blockIdx.x * 256 + t;
    unsigned long long hv = (n < N) ? hist[n] : 0ULL;
    int c = (n < N) ? (int)(hv >> CNT_SHIFT) + 1 : 0;
    // inclusive scan within wave
    int v = c;
#pragma unroll
    for (int m = 1; m < 64; m <<= 1) {
        int u = __shfl_up(v, m);
        if (lane >= m) v += u;
    }
    __shared__ int wsum[4];
    if (lane == 63) wsum[t >> 6] = v;
    __syncthreads();
    int w = t >> 6;
    int wadd = 0;
#pragma unroll
    for (int i = 0; i < 3; i++) wadd += (i < w) ? wsum[i] : 0;
    int base = block_off[blockIdx.x] + wadd + v - c;  // exclusive position
    if (n < N) {
        row_ptr[n] = base;
        float asum = (float)(hv & SUM_MASK) * FIX_INV;
        float la = asum / fmaxf((float)(c - 1), 1.f);  // fill_value='mean' self-loop attr
        col[base] = make_int2(n, __float_as_int(la));   // self loop first in row
    }
}

// Pass 2: atomic-free placement (slot was captured in pass 1).
__global__ void place_kernel(const int* __restrict__ src, const int* __restrict__ dst,
                             const float* __restrict__ eattr, const int* __restrict__ row_ptr,
                             const int* __restrict__ pos, int2* __restrict__ col, int E) {
    int e = blockIdx.x * blockDim.x + threadIdx.x;
    if (e < E) {
        int d = dst[e];
        col[row_ptr[d] + 1 + pos[e]] = make_int2(src[e], __float_as_int(eattr[e]));
    }
}

// ---------------- prep: transpose W's (for scalar streaming) + we_dot scalars ----------------

__global__ __launch_bounds__(256) void prep_kernel(
        const float* __restrict__ W1, const float* __restrict__ W2,
        const float* __restrict__ We1, const float* __restrict__ ae1,
        const float* __restrict__ We2, const float* __restrict__ ae2,
        float* __restrict__ Wt1, float* __restrict__ Wt2, float* __restrict__ we_dot) {
    int t = threadIdx.x;
    if (t < 128) {
#pragma unroll
        for (int k = 0; k < 5; k++)  Wt1[t * 5 + k]  = W1[k * 128 + t];
#pragma unroll
        for (int k = 0; k < 64; k++) Wt2[t * 64 + k] = W2[k * 128 + t];
    }
    int g = t >> 6, lane = t & 63;          // g = layer*2 + h
    const float* We = (g & 2) ? We2 : We1;
    const float* ae = (g & 2) ? ae2 : ae1;
    int h = g & 1;
    float v = We[h * 64 + lane] * ae[h * 64 + lane];
#pragma unroll
    for (int m = 32; m >= 1; m >>= 1) v += __shfl_xor(v, m);
    if (lane == 0) we_dot[g] = v;
}

// ---------------- node projection: lane = node, wave = head; W streamed via scalar loads ----
// xhb[n][w] (w=0..63) packs channels {2w,2w+1} as bf16x2; ch 0-63 = head0, 64-127 = head1.

template<int FIN>
__global__ __launch_bounds__(256) void node_proj2(
        const float* __restrict__ feat, const float* __restrict__ Wt,
        const float* __restrict__ as_, const float* __restrict__ ad_,
        u32* __restrict__ xhb, float* __restrict__ al_s, float* __restrict__ al_d, int N) {
    int lane = threadIdx.x & 63;
    int gw = __builtin_amdgcn_readfirstlane(blockIdx.x * 4 + (threadIdx.x >> 6));
    int h  = gw & 1;            // uniform (SGPR) -> Wt/as/ad reads scalarize
    int nb = gw >> 1;
    int n = nb * 64 + lane;
    if (n >= N) return;

    float f[FIN];
    const float* fr = feat + (size_t)n * FIN;
    if constexpr (FIN == 64) {
        const float4* f4 = (const float4*)fr;
#pragma unroll
        for (int q = 0; q < 16; q++) {
            float4 v = f4[q];
            f[4*q] = v.x; f[4*q+1] = v.y; f[4*q+2] = v.z; f[4*q+3] = v.w;
        }
    } else {
#pragma unroll
        for (int k = 0; k < FIN; k++) f[k] = fr[k];
    }

    const float* wbase = Wt + (size_t)(h * 64) * FIN;   // this head's 64 output rows
    const float* asl = as_ + h * 64;
    const float* adl = ad_ + h * 64;
    float vs = 0.f, vd = 0.f;
    u32* dst = xhb + (size_t)n * 64 + h * 32;

    for (int j4 = 0; j4 < 64; j4 += 4) {
        const float* w0 = wbase + (size_t)j4 * FIN;
        float o0 = 0.f, o1 = 0.f, o2 = 0.f, o3 = 0.f;
#pragma unroll
        for (int k = 0; k < FIN; k++) {
            float fk = f[k];
            o0 += fk * w0[k];
            o1 += fk * w0[FIN + k];
            o2 += fk * w0[2 * FIN + k];
            o3 += fk * w0[3 * FIN + k];
        }
        vs += o0 * asl[j4] + o1 * asl[j4+1] + o2 * asl[j4+2] + o3 * asl[j4+3];
        vd += o0 * adl[j4] + o1 * adl[j4+1] + o2 * adl[j4+2] + o3 * adl[j4+3];
        uint2 pw = make_uint2((f2bf(o1) << 16) | f2bf(o0), (f2bf(o3) << 16) | f2bf(o2));
        *((uint2*)(dst + (j4 >> 1))) = pw;
    }
    al_s[n * 2 + h] = vs;
    al_d[n * 2 + h] = vd;
}

// ---------------- edge aggregation: wave per dst node, 4 waves/block ----------------
// LDS broadcast for per-edge weights (per-wave slices, no barriers: same-wave LDS rw).
// lane owns packed word `lane` = channels {2*lane,2*lane+1}; lanes<32 head0, lanes>=32 head1.

__global__ __launch_bounds__(256) void edge_aggr2(
        const int* __restrict__ row_ptr, const int2* __restrict__ col,
        const float2* __restrict__ al_s, const float2* __restrict__ al_d,
        const u32* __restrict__ xhb,
        const float* __restrict__ bias, const float* __restrict__ we_dot, int layer,
        float* __restrict__ out, int N) {
    __shared__ float s_ex0[4][64], s_ex1[4][64];
    __shared__ int s_src[4][64];
    int wid = threadIdx.x >> 6;
    int lane = threadIdx.x & 63;
    int n = blockIdx.x * 4 + wid;
    if (n >= N) return;
    int start = row_ptr[n], end = row_ptr[n + 1];
    int cnt = end - start;
    float we0 = we_dot[layer * 2], we1 = we_dot[layer * 2 + 1];
    float2 ald = al_d[n];
    bool lo = lane < 32;

    float accx = 0.f, accy = 0.f, den0 = 0.f, den1 = 0.f;

    if (cnt <= 64) {
        // ---- fast path: single chunk, alpha computed once ----
        float a0 = -INFINITY, a1 = -INFINITY;
        int sc = 0;
        if (lane < cnt) {
            int2 ce = col[start + lane];
            sc = ce.x;
            float at = __int_as_float(ce.y);
            float2 als = al_s[sc];
            a0 = LRELU(als.x + ald.x + we0 * at);
            a1 = LRELU(als.y + ald.y + we1 * at);
        }
        float m0 = a0, m1 = a1;
#pragma unroll
        for (int m = 32; m >= 1; m >>= 1) {
            m0 = fmaxf(m0, __shfl_xor(m0, m));
            m1 = fmaxf(m1, __shfl_xor(m1, m));
        }
        float e0 = 0.f, e1 = 0.f;
        if (lane < cnt) {
            e0 = __expf(a0 - m0);
            e1 = __expf(a1 - m1);
        }
        den0 = e0; den1 = e1;
        s_ex0[wid][lane] = e0; s_ex1[wid][lane] = e1; s_src[wid][lane] = sc;
        // no barrier: same-wave LDS write->read, lockstep

        const float* s_w = lo ? s_ex0[wid] : s_ex1[wid];
#pragma unroll 4
        for (int j = 0; j < cnt; j++) {
            float w = s_w[j];
            u32 v = xhb[(size_t)s_src[wid][j] * 64 + lane];
            accx += w * __uint_as_float(v << 16);
            accy += w * __uint_as_float(v & 0xffff0000u);
        }
    } else {
        // ---- general path (cnt > 64): chunked, same LDS broadcast ----
        float m0 = -INFINITY, m1 = -INFINITY;
        for (int i = start + lane; i < end; i += 64) {
            int2 ce = col[i];
            float at = __int_as_float(ce.y);
            float2 als = al_s[ce.x];
            m0 = fmaxf(m0, LRELU(als.x + ald.x + we0 * at));
            m1 = fmaxf(m1, LRELU(als.y + ald.y + we1 * at));
        }
#pragma unroll
        for (int m = 32; m >= 1; m >>= 1) {
            m0 = fmaxf(m0, __shfl_xor(m0, m));
            m1 = fmaxf(m1, __shfl_xor(m1, m));
        }
        const float* s_w = lo ? s_ex0[wid] : s_ex1[wid];
        for (int cs = start; cs < end; cs += 64) {
            int i = cs + lane;
            float e0 = 0.f, e1 = 0.f;
            int sc = 0;
            if (i < end) {
                int2 ce = col[i];
                sc = ce.x;
                float at = __int_as_float(ce.y);
                float2 als = al_s[sc];
                e0 = __expf(LRELU(als.x + ald.x + we0 * at) - m0);
                e1 = __expf(LRELU(als.y + ald.y + we1 * at) - m1);
            }
            den0 += e0; den1 += e1;
            s_ex0[wid][lane] = e0; s_ex1[wid][lane] = e1; s_src[wid][lane] = sc;
            int c2 = min(64, end - cs);
#pragma unroll 4
            for (int j = 0; j < c2; j++) {
                float w = s_w[j];
                u32 v = xhb[(size_t)s_src[wid][j] * 64 + lane];
                accx += w * __uint_as_float(v << 16);
                accy += w * __uint_as_float(v & 0xffff0000u);
            }
        }
    }

#pragma unroll
    for (int m = 32; m >= 1; m >>= 1) {
        den0 += __shfl_xor(den0, m);
        den1 += __shfl_xor(den1, m);
    }
    float inv0 = 1.f / (den0 + 1e-16f), inv1 = 1.f / (den1 + 1e-16f);
    float px = __shfl_xor(accx, 32);   // partner head's partials, same channels
    float py = __shfl_xor(accy, 32);
    if (lo) {
        float2 bv = ((const float2*)bias)[lane];
        float ox = 0.5f * (accx * inv0 + px * inv1) + bv.x;
        float oy = 0.5f * (accy * inv0 + py * inv1) + bv.y;
        ((float2*)out)[(size_t)n * 32 + lane] = make_float2(fmaxf(ox, 0.f), fmaxf(oy, 0.f));
    }
}

// ---------------- pooling: hierarchical (LDS bins -> few global atomics) ----------------

__global__ __launch_bounds__(256) void pool_kernel(const float* __restrict__ feat,
                                                   const float* __restrict__ Wlin, const int* __restrict__ batch,
                                                   float* __restrict__ pool_sum, int* __restrict__ pool_cnt, int N) {
    __shared__ float s_sum[64];
    __shared__ int s_cnt[64];
    int t = threadIdx.x;
    if (t < 64) { s_sum[t] = 0.f; s_cnt[t] = 0; }
    __syncthreads();

    int nblk = gridDim.x;
    int chunk = (N + nblk - 1) / nblk;
    int lo = blockIdx.x * chunk;
    int hi = min(lo + chunk, N);
    int lane = t & 63;
    float wl = Wlin[lane];

    for (int node = lo + (t >> 6); node < hi; node += 4) {
        float v = feat[(size_t)node * 64 + lane] * wl;
#pragma unroll
        for (int m = 32; m >= 1; m >>= 1) v += __shfl_xor(v, m);
        if (lane == 0) {
            int g = batch[node];
            atomicAdd(&s_sum[g], v);
            atomicAdd(&s_cnt[g], 1);
        }
    }
    __syncthreads();
    if (t < 64 && s_cnt[t] > 0) {
        atomicAdd(&pool_sum[t], s_sum[t]);
        atomicAdd(&pool_cnt[t], s_cnt[t]);
    }
}

__global__ void final_kernel(const float* __restrict__ pool_sum, const int* __restrict__ pool_cnt,
                             const float* __restrict__ blin, float* __restrict__ out) {
    int g = threadIdx.x;
    if (g < 64) out[g] = pool_sum[g] / fmaxf((float)pool_cnt[g], 1.f) + blin[0];
}

// ---------------- launch ----------------

extern "C" void kernel_launch(void* const* d_in, const int* in_sizes, int n_in,
                              void* d_out, int out_size, void* d_ws, size_t ws_size,
                              hipStream_t stream) {
    const float* x     = (const float*)d_in[0];
    const int*   ei    = (const int*)d_in[1];
    const float* eattr = (const float*)d_in[2];
    const int*   batch = (const int*)d_in[3];
    const float* W1  = (const float*)d_in[4];
    const float* as1 = (const float*)d_in[5];
    const float* ad1 = (const float*)d_in[6];
    const float* We1 = (const float*)d_in[7];
    const float* ae1 = (const float*)d_in[8];
    const float* b1  = (const float*)d_in[9];
    const float* W2  = (const float*)d_in[10];
    const float* as2 = (const float*)d_in[11];
    const float* ad2 = (const float*)d_in[12];
    const float* We2 = (const float*)d_in[13];
    const float* ae2 = (const float*)d_in[14];
    const float* b2  = (const float*)d_in[15];
    const float* Wlin = (const float*)d_in[16];
    const float* blin = (const float*)d_in[17];
    float* out = (float*)d_out;

    int N = in_sizes[0] / 5;
    int E = in_sizes[1] / 2;
    size_t EP = (size_t)E + N;
    const int* src0 = ei;
    const int* dst0 = ei + E;
    int B = (N + 255) / 256;   // blocks for node-chunked scan (must be <= 1024)

    char* ws = (char*)d_ws;
    size_t off = 0;
    auto alloc = [&](size_t bytes) {
        void* p = ws + off;
        off = (off + bytes + 255) & ~(size_t)255;
        return p;
    };
    unsigned long long* hist = (unsigned long long*)alloc((size_t)N * 8);
    int*   row_ptr  = (int*)  alloc((size_t)(N + 1) * 4);
    int*   pos      = (int*)  alloc((size_t)E * 4);
    int2*  col      = (int2*) alloc(EP * 8);
    int*   block_sum= (int*)  alloc((size_t)1024 * 4);
    int*   block_off= (int*)  alloc((size_t)1024 * 4);
    float* al_s     = (float*)alloc((size_t)N * 2 * 4);
    float* al_d     = (float*)alloc((size_t)N * 2 * 4);
    u32*   xhb      = (u32*)  alloc((size_t)N * 64 * 4);   // packed bf16x2
    float* feat1    = (float*)alloc((size_t)N * 64 * 4);
    float* feat2    = (float*)alloc((size_t)N * 64 * 4);
    float* Wt1      = (float*)alloc((size_t)128 * 5 * 4);
    float* Wt2      = (float*)alloc((size_t)128 * 64 * 4);
    float* we_dot   = (float*)alloc(4 * 4);
    float* pool_sum = (float*)alloc(64 * 4);
    int*   pool_cnt = (int*)  alloc(64 * 4);

    hipMemsetAsync(hist, 0, (size_t)N * 8, stream);
    hipMemsetAsync(block_sum, 0, (size_t)1024 * 4, stream);
    hipMemsetAsync(pool_sum, 0, 64 * 4, stream);
    hipMemsetAsync(pool_cnt, 0, 64 * 4, stream);

    hist_pos_kernel<<<(E + 255) / 256, 256, 0, stream>>>(dst0, eattr, hist, pos, E);
    scan_phase1<<<B, 256, 0, stream>>>(hist, block_sum, N);
    scan_phase2<<<1, 1024, 0, stream>>>(block_sum, block_off, row_ptr, B, N);
    scan_phase3<<<B, 256, 0, stream>>>(hist, block_off, row_ptr, col, N);
    place_kernel<<<(E + 255) / 256, 256, 0, stream>>>(src0, dst0, eattr, row_ptr, pos, col, E);
    prep_kernel<<<1, 256, 0, stream>>>(W1, W2, We1, ae1, We2, ae2, Wt1, Wt2, we_dot);

    int nw = (N + 63) / 64;                 // node-waves per head
    int npb = (2 * nw + 3) / 4;             // blocks for node_proj2 (4 waves each)
    int eab = (N + 3) / 4;                  // blocks for edge_aggr2 (4 waves each)

    // layer 1
    node_proj2<5><<<npb, 256, 0, stream>>>(x, Wt1, as1, ad1, xhb, al_s, al_d, N);
    edge_aggr2<<<eab, 256, 0, stream>>>(row_ptr, col, (const float2*)al_s, (const float2*)al_d,
                                        xhb, b1, we_dot, 0, feat1, N);
    // layer 2
    node_proj2<64><<<npb, 256, 0, stream>>>(feat1, Wt2, as2, ad2, xhb, al_s, al_d, N);
    edge_aggr2<<<eab, 256, 0, stream>>>(row_ptr, col, (const float2*)al_s, (const float2*)al_d,
                                        xhb, b2, we_dot, 1, feat2, N);
    // pool + linear (hierarchical: LDS bins then ~2 global atomics per block)
    pool_kernel<<<512, 256, 0, stream>>>(feat2, Wlin, batch, pool_sum, pool_cnt, N);
    final_kernel<<<1, 64, 0, stream>>>(pool_sum, pool_cnt, blin, out);
}